// Round 6
// baseline (91.056 us; speedup 1.0000x reference)
//
#include <hip/hip_runtime.h>

#define NUM_SEG 256
#define WAY 2
#define NCH 128
#define HW 65536                     // 256*256
#define N_IMG 8
#define PIX_PER_BLK 2048
#define CHUNKS_PER_IMG 32
#define NTHREADS 1024
#define TOTAL_SEG (N_IMG * NUM_SEG)  // 2048
#define NBLOCKS (N_IMG * CHUNKS_PER_IMG)   // 256
#define PART_ELEMS (NUM_SEG * NCH)   // 32768
#define KW 32                        // pixels per K-chunk
#define NITER (PIX_PER_BLK / KW)     // 64
#define LDR 40                       // padded row, shorts (80 B, 16B-aligned)

typedef __attribute__((ext_vector_type(8))) short short8;
typedef __attribute__((ext_vector_type(4))) short short4v;
typedef __attribute__((ext_vector_type(4))) float f32x4;

static __device__ __forceinline__ unsigned short f2bf(float f) {
    unsigned int u = __float_as_uint(f);
    unsigned int r = u + 0x7FFFu + ((u >> 16) & 1u);
    return (unsigned short)(r >> 16);
}

static __device__ __forceinline__ short4v cvt4(float4 v) {
    short4v r;
    r[0] = (short)f2bf(v.x); r[1] = (short)f2bf(v.y);
    r[2] = (short)f2bf(v.z); r[3] = (short)f2bf(v.w);
    return r;
}

// LDS-ordering barrier that does NOT drain vmcnt: outstanding global
// prefetch loads stay in flight across it. All DS ops (writes for the
// nxt buffers, reads feeding this iter's MFMAs) are completed first, so
// the double-buffer RAW/WAR discipline is preserved.
static __device__ __forceinline__ void lds_barrier() {
    asm volatile("s_waitcnt lgkmcnt(0)" ::: "memory");
    __builtin_amdgcn_s_barrier();
    __builtin_amdgcn_sched_barrier(0);
}

// One-hot MFMA segment-sum, dbuf LDS-staged A, vmcnt-preserving barriers.
// C[ch][seg] += F[ch][k] * (seg(k)==seg)
__global__ __launch_bounds__(NTHREADS, 8)
void seg_mfma_kernel(const float* __restrict__ img,
                     const int* __restrict__ mask,
                     const int* __restrict__ segs,
                     float* __restrict__ ws_part,      // [NBLOCKS][PART_ELEMS]
                     int* __restrict__ labcnt_g) {     // [TOTAL_SEG][WAY]
    __shared__ __align__(16) unsigned short OH[2][NUM_SEG][LDR]; // 40 KB one-hot B
    __shared__ __align__(16) unsigned short At[2][NCH][LDR];     // 20 KB bf16 A
    __shared__ unsigned char segb[PIX_PER_BLK];                  // 2 KB
    __shared__ int labc[NUM_SEG * WAY];                          // 2 KB

    const int bid   = blockIdx.x;        // n*32 + chunk
    const int n     = bid >> 5;
    const int chunk = bid & 31;
    const int t     = threadIdx.x;
    const int lane  = t & 63;
    const int w     = t >> 6;            // wave 0..15
    const int mg    = w & 3;             // ch group base 32*mg
    const int ng    = w >> 2;            // seg group base 64*ng

    const long pixbase = (long)n * HW + chunk * PIX_PER_BLK;

    // zero OH (both buffers incl. pads) + labc
    {
        int4 z; z.x = z.y = z.z = z.w = 0;
        int4* p = (int4*)&OH[0][0][0];
        for (int i = t; i < (2 * NUM_SEG * LDR * 2) / 16; i += NTHREADS) p[i] = z;
        for (int i = t; i < NUM_SEG * WAY; i += NTHREADS) labc[i] = 0;
    }
    __syncthreads();

    // stage seg ids (u8) + label histogram
    for (int p = t; p < PIX_PER_BLK; p += NTHREADS) {
        int s = segs[pixbase + p];
        segb[p] = (unsigned char)s;
        atomicAdd(&labc[s * 2 + mask[pixbase + p]], 1);
    }

    // A staging addressing: 8 threads/row, float4 each (32 px/chunk)
    const int arow = t >> 3;             // 0..127
    const int acol = (t & 7) * 4;        // 0..28
    const float* gA = img + (long)(n * NCH + arow) * HW
                          + chunk * PIX_PER_BLK + acol;

    // load chunk 0
    float4 fc = *(const float4*)(gA);
    __syncthreads();                      // segb + OH zeros visible

    // build chunk 0 into At[0], OH[0]
    *(short4v*)&At[0][arow][acol] = cvt4(fc);
    const bool sc = (t < KW);             // wave-0 lanes 0..31 own one-hot cols
    int s_prev = -1, s_cur = -1;
    if (sc) {
        s_cur = segb[t];
        OH[0][s_cur][t] = 0x3F80;         // bf16 1.0
    }
    fc = *(const float4*)(gA + KW);       // issue load chunk 1
    __syncthreads();                      // At[0], OH[0] visible

    f32x4 acc[2][4] = {};
    const int l15 = lane & 15;
    const int kA  = 8 * (lane >> 4);

    for (int it = 0; it < NITER; ++it) {
        const int cur = it & 1, nxt = cur ^ 1;

        // issue load for chunk it+2 (stays in flight across the barrier)
        float4 fn = fc;
        if (it + 2 < NITER) fn = *(const float4*)(gA + (it + 2) * KW);
        int s_next = 0;
        if (sc && it + 1 < NITER) s_next = segb[(it + 1) * KW + t];

        // MFMA on chunk it (reads cur buffers only)
        short8 a0 = *(const short8*)&At[cur][32 * mg      + l15][kA];
        short8 a1 = *(const short8*)&At[cur][32 * mg + 16 + l15][kA];
        #pragma unroll
        for (int nj = 0; nj < 4; ++nj) {
            short8 b = *(const short8*)&OH[cur][64 * ng + 16 * nj + l15][kA];
            acc[0][nj] = __builtin_amdgcn_mfma_f32_16x16x32_bf16(a0, b, acc[0][nj], 0, 0, 0);
            acc[1][nj] = __builtin_amdgcn_mfma_f32_16x16x32_bf16(a1, b, acc[1][nj], 0, 0, 0);
        }

        // stage chunk it+1 into nxt buffers (disjoint from cur)
        if (it + 1 < NITER) {
            *(short4v*)&At[nxt][arow][acol] = cvt4(fc);   // fc loaded last iter
            if (sc) {
                if (s_prev >= 0 && s_prev != s_next) OH[nxt][s_prev][t] = 0;
                OH[nxt][s_next][t] = 0x3F80;
                s_prev = s_cur;
                s_cur  = s_next;
            }
        }
        lds_barrier();      // lgkmcnt(0)+s_barrier, vmcnt stays outstanding
        fc = fn;
    }

    // epilogue: 4 concurrent 8 KB strips (reuse OH, 32 KB), 4 rounds x 2 barriers
    float (*strips)[16 * NCH] = (float (*)[16 * NCH])&OH[0][0][0];
    float* wsb = ws_part + (long)bid * PART_ELEMS;
    #pragma unroll
    for (int nj = 0; nj < 4; ++nj) {      // unrolled: acc index compile-time
        // wave (mg,ng) writes its tile into strip[ng]
        // D layout: col(seg-local)=lane&15, row(ch-local)=4*(lane>>4)+r
        #pragma unroll
        for (int m = 0; m < 2; ++m)
            #pragma unroll
            for (int r = 0; r < 4; ++r)
                strips[ng][l15 * NCH + 32 * mg + 16 * m + 4 * (lane >> 4) + r] =
                    acc[m][nj][r];
        __syncthreads();
        {   // copy all 4 strips: thread t -> strip t>>8, 8 floats at (t&255)*8
            const int sidx = t >> 8;
            const int off  = (t & 255) * 8;
            const float4* src = (const float4*)&strips[sidx][off];
            float4 v0 = src[0], v1 = src[1];
            float* dst = wsb + (64 * sidx + 16 * nj) * NCH + off;
            ((float4*)dst)[0] = v0;
            ((float4*)dst)[1] = v1;
        }
        __syncthreads();
    }

    for (int i = t; i < NUM_SEG * WAY; i += NTHREADS)
        atomicAdd(&labcnt_g[n * NUM_SEG * WAY + i], labc[i]);
}

// sum 32 chunk-partials, divide by count, emit labels
__global__ void reduce_ws_kernel(const float* __restrict__ ws_part,
                                 const int* __restrict__ labcnt,
                                 float* __restrict__ out) {
    const int nmean = TOTAL_SEG * NCH;    // 262144
    int i = blockIdx.x * blockDim.x + threadIdx.x;
    if (i < nmean) {
        int nimg = i >> 15;               // / 32768
        int rem  = i & 32767;             // s*128 + c
        const float* base = ws_part + (long)nimg * 32 * PART_ELEMS + rem;
        float acc = 0.0f;
        #pragma unroll
        for (int j = 0; j < CHUNKS_PER_IMG; ++j)
            acc += base[(long)j * PART_ELEMS];
        int g  = i >> 7;                  // n*256 + s
        int c0 = labcnt[g * 2 + 0];
        int c1 = labcnt[g * 2 + 1];
        out[i] = acc / fmaxf((float)(c0 + c1), 1.0f);
    } else if (i < nmean + TOTAL_SEG) {
        int g = i - nmean;
        out[i] = (labcnt[g * 2 + 1] > labcnt[g * 2 + 0]) ? 1.0f : 0.0f;
    }
}

extern "C" void kernel_launch(void* const* d_in, const int* in_sizes, int n_in,
                              void* d_out, int out_size, void* d_ws, size_t ws_size,
                              hipStream_t stream) {
    const float* img  = (const float*)d_in[0];   // (8,128,256,256) f32
    const int*   mask = (const int*)d_in[1];     // (8,256,256) i32 in [0,2)
    const int*   segs = (const int*)d_in[2];     // (8,256,256) i32 in [0,256)

    float* out = (float*)d_out;

    const size_t part_bytes = (size_t)NBLOCKS * PART_ELEMS * sizeof(float); // 32 MB
    float* ws_part = (float*)d_ws;
    int*   labcnt  = (int*)((char*)d_ws + part_bytes);

    hipMemsetAsync(labcnt, 0, (size_t)TOTAL_SEG * WAY * sizeof(int), stream);

    seg_mfma_kernel<<<NBLOCKS, NTHREADS, 0, stream>>>(
        img, mask, segs, ws_part, labcnt);

    const int totalThreads = TOTAL_SEG * NCH + TOTAL_SEG;   // 264192
    reduce_ws_kernel<<<(totalThreads + 255) / 256, 256, 0, stream>>>(
        ws_part, labcnt, out);
}